// Round 2
// baseline (7433.289 us; speedup 1.0000x reference)
//
#include <hip/hip_runtime.h>

// Deep Kalman Filter inference, MI355X/gfx950.
// Phases: pack (weights -> fp16 MFMA-fragment order), fused cooperative
// scan (64 WG = 16 batch-groups x 4 K-split WGs, flag-synced via L2),
// parallel transition/emitter/loss (2048 WG), finalize.

#define T_LEN 512
#define BATCH 256
#define DIMX  128
#define ZDIM  128
#define TRD   256
#define EMD   256
#define RHD   512
#define NS    4      // K-split WGs per batch group

typedef _Float16 f16;
typedef _Float16 f16x4 __attribute__((ext_vector_type(4)));
typedef _Float16 f16x8 __attribute__((ext_vector_type(8)));
typedef float    f32x4 __attribute__((ext_vector_type(4)));

#define MFMA16(a,b,c) __builtin_amdgcn_mfma_f32_16x16x32_f16((a),(b),(c),0,0,0)

// ---- packed weight element offsets (f16 elements) ----
#define PK_WIH  0u
#define PK_WHH  65536u
#define PK_G1   327680u
#define PK_G2   360448u
#define PK_P1   393216u
#define PK_P2   425984u
#define PK_TMU  458752u
#define PK_TLV  475136u
#define PK_CBH  491520u
#define PK_CBML 557056u
#define PK_E1   688128u
#define PK_E2   720896u
#define PK_EMU  786432u

// ---- workspace byte offsets ----
#define WS_Z    0ull                          // f16 [T+1][B][Z]
#define WS_MU   (WS_Z   + 33619968ull)        // f16 [T][B][Z]
#define WS_LV   (WS_MU  + 33554432ull)        // f16 [T][B][Z]
#define WS_PK   (WS_LV  + 33554432ull)        // f16 packed weights
#define WS_PART (WS_PK  + 1638400ull)         // f32 [2048][2]
#define WS_EXCH (WS_PART + 16384ull)          // f16 exchange, 160KB/group x16
#define WS_CTR  (WS_EXCH + 2621440ull)        // u32 counters, 128B/group
#define WS_END  (WS_CTR + 2048ull)

// =====================================================================
// helpers
// =====================================================================
__device__ __forceinline__ void ldsfence() {
  asm volatile("s_waitcnt lgkmcnt(0)" ::: "memory");
  __builtin_amdgcn_sched_barrier(0);
}

template<int N>
__device__ __forceinline__ void zacc(f32x4* a) {
  f32x4 z = {0.f, 0.f, 0.f, 0.f};
#pragma unroll
  for (int i = 0; i < N; ++i) a[i] = z;
}

__device__ __forceinline__ f16x8 cvt8(const float* p) {
  float4 a = *(const float4*)p, b = *(const float4*)(p + 4);
  f16x8 r;
  r[0] = (f16)a.x; r[1] = (f16)a.y; r[2] = (f16)a.z; r[3] = (f16)a.w;
  r[4] = (f16)b.x; r[5] = (f16)b.y; r[6] = (f16)b.z; r[7] = (f16)b.w;
  return r;
}

__device__ __forceinline__ void acc8(float* d, f16x8 v) {
#pragma unroll
  for (int j = 0; j < 8; ++j) d[j] += (float)v[j];
}

// group-local barrier across NS WGs: release-add, spin, acquire.
__device__ __forceinline__ void gsync(unsigned* ctr, unsigned target) {
  __syncthreads();  // WG stores drained (compiler emits vmcnt(0) before s_barrier)
  if (threadIdx.x == 0) {
    __hip_atomic_fetch_add(ctr, 1u, __ATOMIC_RELEASE, __HIP_MEMORY_SCOPE_AGENT);
    while (__hip_atomic_load(ctr, __ATOMIC_RELAXED, __HIP_MEMORY_SCOPE_AGENT) < target)
      __builtin_amdgcn_s_sleep(2);
    __builtin_amdgcn_fence(__ATOMIC_ACQUIRE, "agent");
  }
  __syncthreads();
}

// A-operand fragment load from LDS tile [16][stride] (row = lane&15). (dpar)
template<int KS>
__device__ __forceinline__ void load_af(const f16* src, int sstr, int lane, f16x8* af) {
#pragma unroll
  for (int ks = 0; ks < KS; ++ks)
    af[ks] = *(const f16x8*)(src + (lane & 15) * sstr + ks * 32 + ((lane >> 4) << 3));
}

template<int KS, int NT>
__device__ __forceinline__ void gemm_regA(const f16x8* af, const f16* __restrict__ bp,
                                          int lane, f32x4* acc) {
#pragma unroll
  for (int ks = 0; ks < KS; ++ks)
#pragma unroll
    for (int j = 0; j < NT; ++j) {
      f16x8 bf = *(const f16x8*)(bp + (((size_t)(ks * NT + j)) << 9) + (lane << 3));
      acc[j] = MFMA16(af[ks], bf, acc[j]);
    }
}

template<int NT>
__device__ __forceinline__ void store_relu(const f32x4* acc, const float* __restrict__ bias,
                                           f16* dst, int dstr, int lane) {
  int colv = lane & 15, rb = (lane >> 4) << 2;
#pragma unroll
  for (int j = 0; j < NT; ++j)
#pragma unroll
    for (int r = 0; r < 4; ++r)
      dst[(rb + r) * dstr + j * 16 + colv] = (f16)fmaxf(acc[j][r] + bias[j * 16 + colv], 0.f);
}

// =====================================================================
// pack: W[K][N] fp32 -> fp16 fragments (frag fi = ks*(N/16) + nt).
// Serves as B-operand frags, or equivalently A-operand frags of W^T.
// =====================================================================
__global__ void pack_kernel(const float* __restrict__ s1, const float* __restrict__ s2,
                            int nsplit, int K, int N, f16* __restrict__ dst) {
  int idx = blockIdx.x * 256 + threadIdx.x;
  if (idx >= K * N) return;
  int j = idx & 7, l = (idx >> 3) & 63, fi = idx >> 9;
  int NTt = N >> 4;
  int nt = fi % NTt, ks = fi / NTt;
  int k = ks * 32 + ((l >> 4) << 3) + j;
  int n = (nt << 4) + (l & 15);
  float v;
  if (n < nsplit) v = s1[(size_t)k * nsplit + n];
  else            v = s2[(size_t)k * (N - nsplit) + (n - nsplit)];
  dst[idx] = (f16)v;
}

__global__ void zero_ctr_kernel(unsigned* __restrict__ c) { c[threadIdx.x] = 0; }

// =====================================================================
// Fused cooperative scan. 64 WGs x 256 threads (4 waves).
// blockIdx: g = bx&15 (batch group, rows g*16..), s = bx>>4 (K-split slice)
//  -> group members share bx%8 (same-XCD heuristic; perf only).
// WG s owns: h/hc cols Hs=[128s,128s+128), z cols Zs=[32s,32s+32).
// Per step t:
//  P0: xw = x_t @ Wih[:,Hs]          (full K=128, own slice, no exchange)
//  P1: partH_s = h[:,Hs] @ Whh[Hs,:] (LDS-resident slice)
//  P2: partC_s = z[:,Zs] @ cbh[Zs,:] (reg-resident A-frags)
//     -> write partH/partC (f16), syncA
//  epilogue: h = relu(xw+bias+SUM partH); hc = 0.5*(tanh(SUM partC+chb)+h)
//  P3: partM_s = hc[:,Hs] @ cbml[Hs,:] (reg-resident A-frags)
//     -> write partM, syncB
//  z-epilogue: z = mu + eps*exp(0.5*lv); store z/mu/lv slices.
// All GEMMs swapped (weights=A, batch=N=16): C-frag = 4 consecutive outdims
// per lane -> 8B packed exchange writes, 16B frag gathers. No transposes.
// =====================================================================
__global__ __launch_bounds__(256, 1) void scan_kernel(
    const float* __restrict__ x, const f16* __restrict__ pk,
    const float* __restrict__ bih, const float* __restrict__ bhh,
    const float* __restrict__ h0, const float* __restrict__ zq0,
    const float* __restrict__ chb, const float* __restrict__ cmb,
    const float* __restrict__ clb, const float* __restrict__ eps_comb,
    f16* __restrict__ z_all, f16* __restrict__ mu_all, f16* __restrict__ lv_all,
    f16* __restrict__ exch, unsigned* __restrict__ ctrs) {
  __shared__ __align__(16) f16 whh_lds[65536];  // 128 KB: Whh rows [Hs,Hs+128)
  __shared__ __align__(16) f16 xw_st[2048];     // [16][128] f16
  __shared__ __align__(16) f16 h_st[2048];
  __shared__ __align__(16) f16 hc_st[2048];

  const int tid = threadIdx.x, lane = tid & 63, w = tid >> 6;
  const int g = blockIdx.x & 15, s = blockIdx.x >> 4;
  const int b0 = g * 16, colv = lane & 15, l4 = lane >> 4;
  const int Hs0 = s * 128, Zs0 = s * 32;

  // stage Whh K-slice into LDS (frag chunk is contiguous in packed buffer)
  {
    const uint4* src = (const uint4*)(pk + PK_WHH + (size_t)s * 65536);
    uint4* dst = (uint4*)whh_lds;
    for (int i = tid; i < 8192; i += 256) dst[i] = src[i];
  }

  // t-invariant A-fragments held in registers (112 VGPRs)
  f16x8 cbhA[8];
#pragma unroll
  for (int m = 0; m < 8; ++m)
    cbhA[m] = *(const f16x8*)(pk + PK_CBH + ((size_t)(s * 32 + w * 8 + m)) * 512 + lane * 8);
  f16x8 cbmlA[4][4];  // [mt][ks]
#pragma unroll
  for (int m = 0; m < 4; ++m)
#pragma unroll
    for (int ks = 0; ks < 4; ++ks)
      cbmlA[m][ks] = *(const f16x8*)(pk + PK_CBML + ((size_t)((4 * s + ks) * 16 + w * 4 + m)) * 512 + lane * 8);
  f16x8 wihA[2][4];
#pragma unroll
  for (int m = 0; m < 2; ++m)
#pragma unroll
    for (int ks = 0; ks < 4; ++ks)
      wihA[m][ks] = *(const f16x8*)(pk + PK_WIH + ((size_t)(ks * 32 + 8 * s + w * 2 + m)) * 512 + lane * 8);

  // epilogue constants: thread i owns slice row=i>>4, local cols (i&15)*8..+8
  const int ec0 = (tid & 15) * 8;
  float bsum[8], chbv[8];
#pragma unroll
  for (int j = 0; j < 8; ++j) {
    int c = Hs0 + ec0 + j;
    bsum[j] = bih[c] + bhh[c];
    chbv[j] = chb[c];
  }
  float cmbv[8], clbv[8];
#pragma unroll
  for (int j = 0; j < 8; ++j) {
    int c = Zs0 + l4 * 8 + j;
    cmbv[j] = cmb[c]; clbv[j] = clb[c];
  }

  // B-frag state: h[colv][Hs-slice], z[colv][Zs-slice]
  f16x8 hB[4], zB;
#pragma unroll
  for (int ks = 0; ks < 4; ++ks) hB[ks] = cvt8(h0 + Hs0 + ks * 32 + l4 * 8);
  zB = cvt8(zq0 + Zs0 + l4 * 8);

  // exchange bases (f16 elements): per group 160KB
  f16* exg = exch + (size_t)g * 81920;
  f16* eH = exg;            // [4 slots][16][512]
  f16* eC = exg + 32768;    // [4 slots][16][512]
  f16* eM = exg + 65536;    // [4 slots][16][256]
  unsigned* ctr = ctrs + g * 32;

  if (w == 0)
    *(f16x8*)(z_all + (size_t)(b0 + colv) * ZDIM + Zs0 + l4 * 8) = zB;  // z_all[0]

  __syncthreads();

  unsigned tgt = 0;
#pragma unroll 1
  for (int t = 0; t < T_LEN; ++t) {
    // t-dependent input gathers (issued early; consumed later)
    f16x8 xBf[4];
#pragma unroll
    for (int ks = 0; ks < 4; ++ks)
      xBf[ks] = cvt8(x + ((size_t)(b0 + colv) * T_LEN + t) * DIMX + ks * 32 + l4 * 8);
    const float* epp = eps_comb + ((size_t)t * BATCH + b0 + colv) * ZDIM + Zs0 + l4 * 8;
    float4 ep0 = *(const float4*)epp;
    float4 ep1 = *(const float4*)(epp + 4);

    // P0: xw (full-K, own M-slice 128)
    f32x4 acc0[2]; zacc<2>(acc0);
#pragma unroll
    for (int ks = 0; ks < 4; ++ks)
#pragma unroll
      for (int m = 0; m < 2; ++m)
        acc0[m] = MFMA16(wihA[m][ks], xBf[ks], acc0[m]);
    // P1: h-partial (M=512)
    f32x4 acc1[8]; zacc<8>(acc1);
#pragma unroll
    for (int ks = 0; ks < 4; ++ks)
#pragma unroll
      for (int m = 0; m < 8; ++m)
        acc1[m] = MFMA16(*(const f16x8*)(whh_lds + (ks * 32 + w * 8 + m) * 512 + lane * 8),
                         hB[ks], acc1[m]);
    // P2: combiner-hidden partial (M=512, K=32 slice of z)
    f32x4 acc2[8]; zacc<8>(acc2);
#pragma unroll
    for (int m = 0; m < 8; ++m)
      acc2[m] = MFMA16(cbhA[m], zB, acc2[m]);

    // writes: xw -> LDS stage; partH/partC -> exchange (f16x4 packed)
#pragma unroll
    for (int m = 0; m < 2; ++m) {
      f16x4 v;
#pragma unroll
      for (int r = 0; r < 4; ++r) v[r] = (f16)acc0[m][r];
      *(f16x4*)(xw_st + colv * 128 + (w * 2 + m) * 16 + l4 * 4) = v;
    }
#pragma unroll
    for (int m = 0; m < 8; ++m) {
      f16x4 v;
#pragma unroll
      for (int r = 0; r < 4; ++r) v[r] = (f16)acc1[m][r];
      *(f16x4*)(eH + s * 8192 + colv * 512 + (w * 8 + m) * 16 + l4 * 4) = v;
    }
#pragma unroll
    for (int m = 0; m < 8; ++m) {
      f16x4 v;
#pragma unroll
      for (int r = 0; r < 4; ++r) v[r] = (f16)acc2[m][r];
      *(f16x4*)(eC + s * 8192 + colv * 512 + (w * 8 + m) * 16 + l4 * 4) = v;
    }

    gsync(ctr, tgt += NS);  // sync A

    // h/hc epilogue (per thread: row=tid>>4, cols Hs0+ec0..+8)
    {
      const int row = tid >> 4;
      float hsum[8], csum[8];
#pragma unroll
      for (int j = 0; j < 8; ++j) { hsum[j] = bsum[j]; csum[j] = chbv[j]; }
#pragma unroll
      for (int sl = 0; sl < 4; ++sl) {
        acc8(hsum, *(const f16x8*)(eH + sl * 8192 + row * 512 + Hs0 + ec0));
        acc8(csum, *(const f16x8*)(eC + sl * 8192 + row * 512 + Hs0 + ec0));
      }
      f16x8 xwv = *(const f16x8*)(xw_st + row * 128 + ec0);
      f16x8 h8, hc8;
#pragma unroll
      for (int j = 0; j < 8; ++j) {
        float hv = fmaxf(hsum[j] + (float)xwv[j], 0.f);
        float tt = __builtin_amdgcn_exp2f(csum[j] * 2.885390082f);  // e^(2x)
        float th = 1.f - 2.f * __builtin_amdgcn_rcpf(tt + 1.f);     // tanh
        h8[j] = (f16)hv;
        hc8[j] = (f16)(0.5f * (th + hv));
      }
      *(f16x8*)(h_st + row * 128 + ec0) = h8;
      *(f16x8*)(hc_st + row * 128 + ec0) = hc8;
    }
    __syncthreads();

    // reload B-frags (broadcast-friendly LDS reads)
    f16x8 hcB[4];
#pragma unroll
    for (int ks = 0; ks < 4; ++ks) {
      hB[ks]  = *(const f16x8*)(h_st  + colv * 128 + ks * 32 + l4 * 8);
      hcB[ks] = *(const f16x8*)(hc_st + colv * 128 + ks * 32 + l4 * 8);
    }

    // P3: (mu|lv) partial (M=256, K=128 slice of hc)
    f32x4 acc3[4]; zacc<4>(acc3);
#pragma unroll
    for (int ks = 0; ks < 4; ++ks)
#pragma unroll
      for (int m = 0; m < 4; ++m)
        acc3[m] = MFMA16(cbmlA[m][ks], hcB[ks], acc3[m]);
#pragma unroll
    for (int m = 0; m < 4; ++m) {
      f16x4 v;
#pragma unroll
      for (int r = 0; r < 4; ++r) v[r] = (f16)acc3[m][r];
      *(f16x4*)(eM + s * 4096 + colv * 256 + (w * 4 + m) * 16 + l4 * 4) = v;
    }

    gsync(ctr, tgt += NS);  // sync B

    // z epilogue (per lane; redundant across waves)
    {
      float mu[8], lv[8];
#pragma unroll
      for (int j = 0; j < 8; ++j) { mu[j] = cmbv[j]; lv[j] = clbv[j]; }
#pragma unroll
      for (int sl = 0; sl < 4; ++sl) {
        acc8(mu, *(const f16x8*)(eM + sl * 4096 + colv * 256 + Zs0 + l4 * 8));
        acc8(lv, *(const f16x8*)(eM + sl * 4096 + colv * 256 + 128 + Zs0 + l4 * 8));
      }
      float ep[8] = {ep0.x, ep0.y, ep0.z, ep0.w, ep1.x, ep1.y, ep1.z, ep1.w};
      f16x8 z8, mu8, lv8;
#pragma unroll
      for (int j = 0; j < 8; ++j) {
        float zv = mu[j] + ep[j] * __builtin_amdgcn_exp2f(lv[j] * 0.7213475204f);
        z8[j] = (f16)zv; mu8[j] = (f16)mu[j]; lv8[j] = (f16)lv[j];
      }
      zB = z8;
      if (w == 0) {
        size_t o = ((size_t)t * BATCH + b0 + colv) * ZDIM + Zs0 + l4 * 8;
        *(f16x8*)(z_all + o + (size_t)BATCH * ZDIM) = z8;  // slot t+1
        *(f16x8*)(mu_all + o) = mu8;
        *(f16x8*)(lv_all + o) = lv8;
      }
    }
  }
}

// =====================================================================
// Phase D: parallel transition/emitter/losses over all (t,b). (unchanged)
// =====================================================================
__global__ __launch_bounds__(256) void dpar_kernel(
    const f16* __restrict__ z_all, const f16* __restrict__ mu_all,
    const f16* __restrict__ lv_all, const float* __restrict__ y,
    const float* __restrict__ eps_emit, const f16* __restrict__ pk,
    const float* __restrict__ g1b, const float* __restrict__ g2b,
    const float* __restrict__ p1b, const float* __restrict__ p2b,
    const float* __restrict__ tmub, const float* __restrict__ tlvb,
    const float* __restrict__ e1b, const float* __restrict__ e2b,
    const float* __restrict__ emub, const float* __restrict__ em_logvar,
    float* __restrict__ partials) {
  __shared__ __align__(16) f16 sb256[4][16 * 264];
  __shared__ __align__(16) f16 sb128[4][16 * 136];
  __shared__ float wsum[4][2];
  const int tid = threadIdx.x, lane = tid & 63, w = tid >> 6;
  const int colv = lane & 15, rb = (lane >> 4) << 2;
  const int m0 = blockIdx.x * 64 + w * 16;
  const int t = m0 >> 8, b0 = m0 & 255;
  f16* B256 = &sb256[w][0];
  f16* B128 = &sb128[w][0];

  f16x8 zp[4], zt[4];
  const f16* zpr = z_all + ((size_t)t * BATCH + b0) * ZDIM;
#pragma unroll
  for (int ks = 0; ks < 4; ++ks) {
    zp[ks] = *(const f16x8*)(zpr + (size_t)colv * ZDIM + ks * 32 + ((lane >> 4) << 3));
    zt[ks] = *(const f16x8*)(zpr + (size_t)BATCH * ZDIM + (size_t)colv * ZDIM + ks * 32 + ((lane >> 4) << 3));
  }

  f32x4 a16[16], a8[8];
  f16x8 af[8], af4[4];
  zacc<16>(a16); gemm_regA<4, 16>(zp, pk + PK_G1, lane, a16);
  store_relu<16>(a16, g1b, B256, 264, lane); ldsfence();
  load_af<8>(B256, 264, lane, af); ldsfence();
  zacc<8>(a8); gemm_regA<8, 8>(af, pk + PK_G2, lane, a8);
  f32x4 gate[8];
#pragma unroll
  for (int j = 0; j < 8; ++j)
#pragma unroll
    for (int r = 0; r < 4; ++r)
      gate[j][r] = 1.f / (1.f + expf(-(a8[j][r] + g2b[j * 16 + colv])));
  zacc<16>(a16); gemm_regA<4, 16>(zp, pk + PK_P1, lane, a16);
  store_relu<16>(a16, p1b, B256, 264, lane); ldsfence();
  load_af<8>(B256, 264, lane, af); ldsfence();
  zacc<8>(a8); gemm_regA<8, 8>(af, pk + PK_P2, lane, a8);
  f32x4 prop[8];
#pragma unroll
  for (int j = 0; j < 8; ++j)
#pragma unroll
    for (int r = 0; r < 4; ++r) {
      float v = a8[j][r] + p2b[j * 16 + colv];
      prop[j][r] = v;
      B128[(rb + r) * 136 + j * 16 + colv] = (f16)fmaxf(v, 0.f);
    }
  ldsfence();
  zacc<8>(a8); gemm_regA<4, 8>(zp, pk + PK_TMU, lane, a8);
  f32x4 prmu[8];
#pragma unroll
  for (int j = 0; j < 8; ++j)
#pragma unroll
    for (int r = 0; r < 4; ++r) {
      float gg = gate[j][r];
      prmu[j][r] = (1.f - gg) * (a8[j][r] + tmub[j * 16 + colv]) + gg * prop[j][r];
    }
  load_af<4>(B128, 136, lane, af4); ldsfence();
  zacc<8>(a8); gemm_regA<4, 8>(af4, pk + PK_TLV, lane, a8);
  f32x4 prlv[8];
#pragma unroll
  for (int j = 0; j < 8; ++j)
#pragma unroll
    for (int r = 0; r < 4; ++r) prlv[j][r] = a8[j][r] + tlvb[j * 16 + colv];
  zacc<16>(a16); gemm_regA<4, 16>(zt, pk + PK_E1, lane, a16);
  store_relu<16>(a16, e1b, B256, 264, lane); ldsfence();
  load_af<8>(B256, 264, lane, af); ldsfence();
  zacc<16>(a16); gemm_regA<8, 16>(af, pk + PK_E2, lane, a16);
  store_relu<16>(a16, e2b, B256, 264, lane); ldsfence();
  load_af<8>(B256, 264, lane, af); ldsfence();
  zacc<8>(a8); gemm_regA<8, 8>(af, pk + PK_EMU, lane, a8);
  float srec = 0.f, skl = 0.f;
#pragma unroll
  for (int j = 0; j < 8; ++j)
#pragma unroll
    for (int r = 0; r < 4; ++r) {
      int row = rb + r, n = j * 16 + colv;
      size_t tb = (size_t)t * BATCH + b0 + row;
      float xt = a8[j][r] + emub[n] + eps_emit[tb * DIMX + n] * expf(0.5f * em_logvar[n]);
      float dy = xt - y[((size_t)(b0 + row) * T_LEN + t) * DIMX + n];
      srec += dy * dy;
      float m_ = (float)mu_all[tb * ZDIM + n], l_ = (float)lv_all[tb * ZDIM + n];
      float dm = m_ - prmu[j][r];
      skl += 0.5f * (prlv[j][r] - l_ + (expf(l_) + dm * dm) * expf(-prlv[j][r]) - 1.f);
    }
#pragma unroll
  for (int off = 32; off; off >>= 1) {
    srec += __shfl_xor(srec, off);
    skl += __shfl_xor(skl, off);
  }
  if (lane == 0) { wsum[w][0] = srec; wsum[w][1] = skl; }
  __syncthreads();
  if (tid == 0) {
    partials[blockIdx.x * 2 + 0] = wsum[0][0] + wsum[1][0] + wsum[2][0] + wsum[3][0];
    partials[blockIdx.x * 2 + 1] = wsum[0][1] + wsum[1][1] + wsum[2][1] + wsum[3][1];
  }
}

// =====================================================================
__global__ void finalize_kernel(const float* __restrict__ partials, float* __restrict__ out) {
  __shared__ float sm[256][2];
  int tid = threadIdx.x;
  float r = 0.f, k = 0.f;
  for (int i = tid; i < 2048; i += 256) {
    r += partials[2 * i];
    k += partials[2 * i + 1];
  }
  sm[tid][0] = r; sm[tid][1] = k;
  __syncthreads();
  for (int off = 128; off; off >>= 1) {
    if (tid < off) { sm[tid][0] += sm[tid + off][0]; sm[tid][1] += sm[tid + off][1]; }
    __syncthreads();
  }
  if (tid == 0) {
    out[0] = sm[0][0] / (131072.f * 128.f);
    out[1] = sm[0][1] / 131072.f;
  }
}

// =====================================================================
extern "C" void kernel_launch(void* const* d_in, const int* in_sizes, int n_in,
                              void* d_out, int out_size, void* d_ws, size_t ws_size,
                              hipStream_t stream) {
  (void)in_sizes; (void)n_in; (void)out_size;
  const float* x        = (const float*)d_in[0];
  const float* y        = (const float*)d_in[1];
  const float* eps_comb = (const float*)d_in[2];
  const float* eps_emit = (const float*)d_in[3];
  const float* wih = (const float*)d_in[4];
  const float* whh = (const float*)d_in[5];
  const float* bih = (const float*)d_in[6];
  const float* bhh = (const float*)d_in[7];
  const float* h0  = (const float*)d_in[8];
  const float* zq0 = (const float*)d_in[9];
  const float* g1W = (const float*)d_in[10]; const float* g1b = (const float*)d_in[11];
  const float* g2W = (const float*)d_in[12]; const float* g2b = (const float*)d_in[13];
  const float* p1W = (const float*)d_in[14]; const float* p1b = (const float*)d_in[15];
  const float* p2W = (const float*)d_in[16]; const float* p2b = (const float*)d_in[17];
  const float* tmuW = (const float*)d_in[18]; const float* tmub = (const float*)d_in[19];
  const float* tlvW = (const float*)d_in[20]; const float* tlvb = (const float*)d_in[21];
  const float* chW = (const float*)d_in[22]; const float* chb = (const float*)d_in[23];
  const float* cmW = (const float*)d_in[24]; const float* cmb = (const float*)d_in[25];
  const float* clW = (const float*)d_in[26]; const float* clb = (const float*)d_in[27];
  const float* e1W = (const float*)d_in[28]; const float* e1b = (const float*)d_in[29];
  const float* e2W = (const float*)d_in[30]; const float* e2b = (const float*)d_in[31];
  const float* emW = (const float*)d_in[32]; const float* emb = (const float*)d_in[33];
  const float* elv = (const float*)d_in[34];

  char* ws = (char*)d_ws;
  f16*  z_all   = (f16*)(ws + WS_Z);
  f16*  mu_all  = (f16*)(ws + WS_MU);
  f16*  lv_all  = (f16*)(ws + WS_LV);
  f16*  pk      = (f16*)(ws + WS_PK);
  float* partials = (float*)(ws + WS_PART);
  f16*  exch    = (f16*)(ws + WS_EXCH);
  unsigned* ctrs = (unsigned*)(ws + WS_CTR);
  float* out = (float*)d_out;
  if (ws_size < WS_END) return;

#define PACK(S1, S2, NS_, K, N, OFF) \
  pack_kernel<<<dim3(((K) * (N)) / 256), dim3(256), 0, stream>>>(S1, S2, NS_, K, N, pk + (OFF))
  PACK(wih, wih, 512, 128, 512, PK_WIH);
  PACK(whh, whh, 512, 512, 512, PK_WHH);
  PACK(g1W, g1W, 256, 128, 256, PK_G1);
  PACK(g2W, g2W, 128, 256, 128, PK_G2);
  PACK(p1W, p1W, 256, 128, 256, PK_P1);
  PACK(p2W, p2W, 128, 256, 128, PK_P2);
  PACK(tmuW, tmuW, 128, 128, 128, PK_TMU);
  PACK(tlvW, tlvW, 128, 128, 128, PK_TLV);
  PACK(chW, chW, 512, 128, 512, PK_CBH);
  PACK(cmW, clW, 128, 512, 256, PK_CBML);
  PACK(e1W, e1W, 256, 128, 256, PK_E1);
  PACK(e2W, e2W, 256, 256, 256, PK_E2);
  PACK(emW, emW, 128, 256, 128, PK_EMU);
#undef PACK

  zero_ctr_kernel<<<dim3(1), dim3(512), 0, stream>>>(ctrs);
  scan_kernel<<<dim3(64), dim3(256), 0, stream>>>(
      x, pk, bih, bhh, h0, zq0, chb, cmb, clb, eps_comb,
      z_all, mu_all, lv_all, exch, ctrs);
  dpar_kernel<<<dim3(2048), dim3(256), 0, stream>>>(z_all, mu_all, lv_all, y, eps_emit, pk,
                                                    g1b, g2b, p1b, p2b, tmub, tlvb, e1b, e2b,
                                                    emb, elv, partials);
  finalize_kernel<<<dim3(1), dim3(256), 0, stream>>>(partials, out);
}